// Round 1
// baseline (1103.880 us; speedup 1.0000x reference)
//
#include <hip/hip_runtime.h>
#include <stdint.h>

#define IN_F    4096
#define OUT_F   16384
#define ACT_IN  2048
#define ACT_OUT 8192
#define NROWS   8192   // B*S = 4*2048

typedef __bf16 bf16;
typedef __bf16 bf16x8 __attribute__((ext_vector_type(8)));
typedef float  f32x4  __attribute__((ext_vector_type(4)));

#define BM 128
#define BN 128
#define BK 32

// ---- async global->LDS, 16B per lane (dest = wave-uniform base + lane*16) ----
__device__ __forceinline__ void g2lds16(const void* g, void* l) {
  __builtin_amdgcn_global_load_lds(
      (const __attribute__((address_space(1))) void*)(uintptr_t)g,
      (__attribute__((address_space(3))) void*)(uint32_t)(uintptr_t)l,
      16, 0, 0);
}

// ---- zero-fill output (capture-safe, float4 stores) ----
__global__ void zero_out_kernel(float* __restrict__ out) {
  size_t i = ((size_t)blockIdx.x * blockDim.x + threadIdx.x) * 4;
  f32x4 z = {0.f, 0.f, 0.f, 0.f};
  *reinterpret_cast<f32x4*>(out + i) = z;
}

// ---- gather active input columns, cast f32 -> bf16 ----
// one block (256 thr) per token row; each thread does 8 consecutive k
__global__ void gather_cast_x(const float* __restrict__ x,
                              const int* __restrict__ in_idx,
                              bf16* __restrict__ A) {
  int n  = blockIdx.x;                 // 0..NROWS-1
  int k0 = threadIdx.x << 3;           // 0..2040 step 8
  const float* xr = x + (size_t)n * IN_F;
  bf16x8 v;
#pragma unroll
  for (int j = 0; j < 8; ++j) v[j] = (bf16)xr[in_idx[k0 + j]];
  *reinterpret_cast<bf16x8*>(A + (size_t)n * ACT_IN + k0) = v;
}

// ---- cast weight f32 -> bf16 (already N x K row-major = gemm_bt layout) ----
__global__ void cast_w_kernel(const float* __restrict__ w, bf16* __restrict__ W) {
  size_t base = ((size_t)blockIdx.x * blockDim.x + threadIdx.x) * 8;
  float4 f0 = *reinterpret_cast<const float4*>(w + base);
  float4 f1 = *reinterpret_cast<const float4*>(w + base + 4);
  bf16x8 v;
  v[0] = (bf16)f0.x; v[1] = (bf16)f0.y; v[2] = (bf16)f0.z; v[3] = (bf16)f0.w;
  v[4] = (bf16)f1.x; v[5] = (bf16)f1.y; v[6] = (bf16)f1.z; v[7] = (bf16)f1.w;
  *reinterpret_cast<bf16x8*>(W + base) = v;
}

// ---- m97-style bf16 GEMM (C = A * W^T), epilogue: +bias, scatter columns ----
__global__ __launch_bounds__(256, 2)
void gemm_scatter(const bf16* __restrict__ A,      // [NROWS][ACT_IN]
                  const bf16* __restrict__ W,      // [ACT_OUT][ACT_IN]
                  const float* __restrict__ bias,  // [ACT_OUT]
                  const int* __restrict__ out_idx, // [ACT_OUT]
                  float* __restrict__ out) {       // [NROWS][OUT_F]
  __shared__ bf16 As[BM * BK];
  __shared__ bf16 Bs[BN * BK];

  const int tid  = threadIdx.x;
  const int lane = tid & 63;
  const int quad = lane >> 4;
  const int l16  = lane & 15;
  const int wave = tid >> 6;
  const int wm   = (wave & 1) << 6;   // 0 or 64 (rows)
  const int wn   = (wave >> 1) << 6;  // 0 or 64 (cols)
  const int m0   = blockIdx.y * BM;
  const int n0   = blockIdx.x * BN;

  // staging coords: 256 thr x 8 elem = 2048 elem/issue; 2 issues per operand
  const int se   = tid << 3;          // element offset within 64x32 half-tile
  const int srow = se >> 5;           // 0..63
  const int scol = se & 31;
  const bf16* Ag0 = A + (size_t)(m0 + srow) * ACT_IN + scol;
  const bf16* Ag1 = Ag0 + (size_t)64 * ACT_IN;
  const bf16* Bg0 = W + (size_t)(n0 + srow) * ACT_IN + scol;
  const bf16* Bg1 = Bg0 + (size_t)64 * ACT_IN;
  bf16* lA0 = As + se;
  bf16* lA1 = As + 64 * BK + se;
  bf16* lB0 = Bs + se;
  bf16* lB1 = Bs + 64 * BK + se;

  f32x4 acc[4][4] = {};

  for (int k0 = 0; k0 < ACT_IN; k0 += BK) {
    g2lds16(Ag0 + k0, lA0);
    g2lds16(Ag1 + k0, lA1);
    g2lds16(Bg0 + k0, lB0);
    g2lds16(Bg1 + k0, lB1);
    __syncthreads();   // compiler emits s_waitcnt vmcnt(0) before s_barrier

    bf16x8 af[4], bfr[4];
#pragma unroll
    for (int i = 0; i < 4; ++i)
      af[i] = *reinterpret_cast<const bf16x8*>(As + (wm + i * 16 + l16) * BK + quad * 8);
#pragma unroll
    for (int j = 0; j < 4; ++j)
      bfr[j] = *reinterpret_cast<const bf16x8*>(Bs + (wn + j * 16 + l16) * BK + quad * 8);

#pragma unroll
    for (int i = 0; i < 4; ++i)
#pragma unroll
      for (int j = 0; j < 4; ++j)
        acc[i][j] = __builtin_amdgcn_mfma_f32_16x16x32_bf16(af[i], bfr[j], acc[i][j], 0, 0, 0);

    __syncthreads();   // protect LDS from next iteration's staging
  }

  // epilogue: C/D layout col = lane&15, row = quad*4 + reg  [m89/m91 verified]
#pragma unroll
  for (int j = 0; j < 4; ++j) {
    const int col = n0 + wn + j * 16 + l16;   // active-output index
    const int oc  = out_idx[col];
    const float b = bias[col];
#pragma unroll
    for (int i = 0; i < 4; ++i) {
      const int row = m0 + wm + i * 16 + (quad << 2);
#pragma unroll
      for (int r = 0; r < 4; ++r)
        out[(size_t)(row + r) * OUT_F + oc] = acc[i][j][r] + b;
    }
  }
}

extern "C" void kernel_launch(void* const* d_in, const int* in_sizes, int n_in,
                              void* d_out, int out_size, void* d_ws, size_t ws_size,
                              hipStream_t stream) {
  const float* x       = (const float*)d_in[0];
  const float* w       = (const float*)d_in[1];
  const float* bias    = (const float*)d_in[2];
  const int*   in_idx  = (const int*)d_in[3];
  const int*   out_idx = (const int*)d_in[4];
  float* out = (float*)d_out;

  bf16* A  = (bf16*)d_ws;                                        // 32 MB
  bf16* Wb = (bf16*)((char*)d_ws + (size_t)NROWS * ACT_IN * 2);  // 32 MB

  // 1) zero the full output (inactive columns must be 0; ws/out are poisoned)
  {
    size_t n4 = (size_t)out_size / 4;            // float4 stores
    zero_out_kernel<<<(uint32_t)(n4 / 256), 256, 0, stream>>>(out);
  }
  // 2) gather + cast activations
  gather_cast_x<<<NROWS, 256, 0, stream>>>(x, in_idx, A);
  // 3) cast weights
  cast_w_kernel<<<(ACT_OUT * (size_t)ACT_IN / 8) / 256, 256, 0, stream>>>(w, Wb);
  // 4) GEMM + bias + scatter
  gemm_scatter<<<dim3(ACT_OUT / BN, NROWS / BM), 256, 0, stream>>>(A, Wb, bias, out_idx, out);
}

// Round 2
// 1025.180 us; speedup vs baseline: 1.0768x; 1.0768x over previous
//
#include <hip/hip_runtime.h>
#include <stdint.h>

#define IN_F    4096
#define OUT_F   16384
#define ACT_IN  2048
#define ACT_OUT 8192
#define NROWS   8192   // B*S = 4*2048

typedef __bf16 bf16;
typedef __bf16 bf16x8 __attribute__((ext_vector_type(8)));
typedef float  f32x4  __attribute__((ext_vector_type(4)));

#define BM 128
#define BN 128
#define BK 32
#define TSTRIDE 34          // f32 tile stride: 4-row quad shift = 136 words %32 = 8 -> 2-way max
#define CMAX 64             // output-col chunk width for the coverage sweep

// ---- async global->LDS, 16B per lane (dest = wave-uniform base + lane*16) ----
__device__ __forceinline__ void g2lds16(const void* g, void* l) {
  __builtin_amdgcn_global_load_lds(
      (const __attribute__((address_space(1))) void*)(uintptr_t)g,
      (__attribute__((address_space(3))) void*)(uint32_t)(uintptr_t)l,
      16, 0, 0);
}

// ---- gather active input columns, cast f32 -> bf16 ----
__global__ void gather_cast_x(const float* __restrict__ x,
                              const int* __restrict__ in_idx,
                              bf16* __restrict__ A) {
  int n  = blockIdx.x;
  int k0 = threadIdx.x << 3;
  const float* xr = x + (size_t)n * IN_F;
  int4 i0 = *reinterpret_cast<const int4*>(in_idx + k0);
  int4 i1 = *reinterpret_cast<const int4*>(in_idx + k0 + 4);
  bf16x8 v;
  v[0] = (bf16)xr[i0.x]; v[1] = (bf16)xr[i0.y];
  v[2] = (bf16)xr[i0.z]; v[3] = (bf16)xr[i0.w];
  v[4] = (bf16)xr[i1.x]; v[5] = (bf16)xr[i1.y];
  v[6] = (bf16)xr[i1.z]; v[7] = (bf16)xr[i1.w];
  *reinterpret_cast<bf16x8*>(A + (size_t)n * ACT_IN + k0) = v;
}

// ---- cast weight f32 -> bf16 (already N x K row-major = gemm_bt layout) ----
__global__ void cast_w_kernel(const float* __restrict__ w, bf16* __restrict__ W) {
  size_t base = ((size_t)blockIdx.x * blockDim.x + threadIdx.x) * 8;
  float4 f0 = *reinterpret_cast<const float4*>(w + base);
  float4 f1 = *reinterpret_cast<const float4*>(w + base + 4);
  bf16x8 v;
  v[0] = (bf16)f0.x; v[1] = (bf16)f0.y; v[2] = (bf16)f0.z; v[3] = (bf16)f0.w;
  v[4] = (bf16)f1.x; v[5] = (bf16)f1.y; v[6] = (bf16)f1.z; v[7] = (bf16)f1.w;
  *reinterpret_cast<bf16x8*>(W + base) = v;
}

// ---- bf16 GEMM (C = A * W^T) with fused zero+bias+scatter coverage epilogue --
// Each block owns active cols [n0, n0+127] and, because out_idx is sorted,
// the contiguous DISJOINT output range (out_idx[n0-1], out_idx[n0+127]]
// (extended to 0 / OUT_F-1 at the edges). It writes EVERY column in that
// range: gathered GEMM values for active cols, zeros for gaps. Union over
// blocks = full output, each element written exactly once -> no zero pass,
// no partial-line RMW.
__global__ __launch_bounds__(256, 2)
void gemm_scatter(const bf16* __restrict__ A,      // [NROWS][ACT_IN]
                  const bf16* __restrict__ W,      // [ACT_OUT][ACT_IN]
                  const float* __restrict__ bias,  // [ACT_OUT]
                  const int* __restrict__ out_idx, // [ACT_OUT]
                  float* __restrict__ out) {       // [NROWS][OUT_F]
  // LDS: K-loop staging (16 KB) unioned with epilogue tile (17 KB) + colmap
  __shared__ __align__(16) char smraw[128 * TSTRIDE * 4 + CMAX * 4];
  bf16* As = (bf16*)smraw;
  bf16* Bs = (bf16*)(smraw + BM * BK * 2);
  float* tile = (float*)smraw;                       // [128][TSTRIDE]
  int*   cmap = (int*)(smraw + 128 * TSTRIDE * 4);   // [CMAX]

  const int tid  = threadIdx.x;
  const int lane = tid & 63;
  const int quad = lane >> 4;
  const int l16  = lane & 15;
  const int wave = tid >> 6;
  const int wm   = (wave & 1) << 6;   // 0 or 64 (rows)
  const int wn   = (wave >> 1) << 6;  // 0 or 64 (cols)
  const int m0   = blockIdx.y * BM;
  const int n0   = blockIdx.x * BN;

  const int se   = tid << 3;          // staging: 256 thr x 8 elem
  const int srow = se >> 5;
  const int scol = se & 31;
  const bf16* Ag0 = A + (size_t)(m0 + srow) * ACT_IN + scol;
  const bf16* Ag1 = Ag0 + (size_t)64 * ACT_IN;
  const bf16* Bg0 = W + (size_t)(n0 + srow) * ACT_IN + scol;
  const bf16* Bg1 = Bg0 + (size_t)64 * ACT_IN;
  bf16* lA0 = As + se;
  bf16* lA1 = As + 64 * BK + se;
  bf16* lB0 = Bs + se;
  bf16* lB1 = Bs + 64 * BK + se;

  f32x4 acc[4][4] = {};

  for (int k0 = 0; k0 < ACT_IN; k0 += BK) {
    g2lds16(Ag0 + k0, lA0);
    g2lds16(Ag1 + k0, lA1);
    g2lds16(Bg0 + k0, lB0);
    g2lds16(Bg1 + k0, lB1);
    __syncthreads();

    bf16x8 af[4], bfr[4];
#pragma unroll
    for (int i = 0; i < 4; ++i)
      af[i] = *reinterpret_cast<const bf16x8*>(As + (wm + i * 16 + l16) * BK + quad * 8);
#pragma unroll
    for (int j = 0; j < 4; ++j)
      bfr[j] = *reinterpret_cast<const bf16x8*>(Bs + (wn + j * 16 + l16) * BK + quad * 8);

#pragma unroll
    for (int i = 0; i < 4; ++i)
#pragma unroll
      for (int j = 0; j < 4; ++j)
        acc[i][j] = __builtin_amdgcn_mfma_f32_16x16x32_bf16(af[i], bfr[j], acc[i][j], 0, 0, 0);

    __syncthreads();
  }

  // ---- epilogue: 4 chunks of 32 active cols; per chunk stage f32 tile in
  // LDS, then dense coalesced coverage sweep (zeros in gaps) ----
  for (int cc = 0; cc < 4; ++cc) {
    __syncthreads();                       // tile free (prev chunk reads done)
    if ((cc >> 1) == (wn >> 6)) {          // waves owning these 32 cols
#pragma unroll
      for (int jj = 0; jj < 2; ++jj) {
        const int j  = ((cc & 1) << 1) + jj;     // C/D col group
        const int cl = (jj << 4) + l16;          // 0..31 within chunk
        const float bv = bias[n0 + wn + j * 16 + l16];
#pragma unroll
        for (int i = 0; i < 4; ++i) {
          const int rb = wm + i * 16 + (quad << 2);
#pragma unroll
          for (int r = 0; r < 4; ++r)
            tile[(rb + r) * TSTRIDE + cl] = acc[i][j][r] + bv;
        }
      }
    }

    const int a0   = n0 + cc * 32;                       // first active idx
    const int lo   = (a0 == 0) ? 0 : out_idx[a0 - 1] + 1;
    const int aend = out_idx[a0 + 31];
    const int hi   = (a0 + 31 == ACT_OUT - 1) ? OUT_F - 1 : aend;

    for (int base = lo; base <= hi; base += CMAX) {      // ~1-2 iters
      int wd = hi - base + 1; if (wd > CMAX) wd = CMAX;
      __syncthreads();
      if (tid < CMAX) cmap[tid] = -1;
      __syncthreads();
      if (tid < 32) {
        int rel = out_idx[a0 + tid] - base;
        if (rel >= 0 && rel < CMAX) cmap[rel] = tid;
      }
      __syncthreads();
      const int lc = tid & 63;
      if (lc < wd) {
        const int cm = cmap[lc];
        size_t ob = (size_t)(m0 + wave * 32) * OUT_F + base + lc;
#pragma unroll 4
        for (int r = 0; r < 32; ++r) {
          float v = (cm >= 0) ? tile[(wave * 32 + r) * TSTRIDE + cm] : 0.0f;
          out[ob + (size_t)r * OUT_F] = v;
        }
      }
    }
  }
}

extern "C" void kernel_launch(void* const* d_in, const int* in_sizes, int n_in,
                              void* d_out, int out_size, void* d_ws, size_t ws_size,
                              hipStream_t stream) {
  const float* x       = (const float*)d_in[0];
  const float* w       = (const float*)d_in[1];
  const float* bias    = (const float*)d_in[2];
  const int*   in_idx  = (const int*)d_in[3];
  const int*   out_idx = (const int*)d_in[4];
  float* out = (float*)d_out;

  bf16* A  = (bf16*)d_ws;                                        // 32 MB
  bf16* Wb = (bf16*)((char*)d_ws + (size_t)NROWS * ACT_IN * 2);  // 32 MB

  gather_cast_x<<<NROWS, 256, 0, stream>>>(x, in_idx, A);
  cast_w_kernel<<<(ACT_OUT * (size_t)ACT_IN / 8) / 256, 256, 0, stream>>>(w, Wb);
  gemm_scatter<<<dim3(ACT_OUT / BN, NROWS / BM), 256, 0, stream>>>(A, Wb, bias, out_idx, out);
}